// Round 1
// baseline (58242.389 us; speedup 1.0000x reference)
//
#include <hip/hip_runtime.h>
#include <math.h>

// ---------------- problem constants ----------------
#define TT   4096
#define BB   9
#define NHc  500
#define NHP  512          // padded hidden dim
#define NMc  6
// ---------------- grid roles ----------------
#define NAg  32           // stage-A WGs (h1), 16 rows each
#define NBg  63           // stage-B WGs (h2), 8 rows each
#define RING 4            // h1/h2 ring depth (steps)
#define IVR  16           // in_vec ring depth
#define WST  516          // LDS weight row stride (bank spread)

// ws layout (float index)
#define WS_CTRA 0
#define WS_CTRB 32
#define WS_CTRC 64
#define WS_RH1  128
#define WS_RH2  (WS_RH1 + RING*BB*NHP)
#define WS_RIV  (WS_RH2 + RING*BB*NHP)   // + IVR*BB*12 -> ~155 KB total

__device__ __forceinline__ bool waitGE(unsigned* p, long long tgt){
  if (tgt <= 0) return true;
  long long n = 0;
  while ((long long)__hip_atomic_load(p, __ATOMIC_RELAXED, __HIP_MEMORY_SCOPE_AGENT) < tgt){
    __builtin_amdgcn_s_sleep(1);
    if (++n > (1LL<<20)) return false;   // safety: wrong answer instead of hang
  }
  return true;
}

extern "C" __global__ void __launch_bounds__(256)
fb_pipe(const float* __restrict__ pert,
        const float* __restrict__ n1g, const float* __restrict__ n2g,
        const float* __restrict__ nmg, const float* __restrict__ homeg,
        const float* __restrict__ Win,  const float* __restrict__ binp,
        const float* __restrict__ Wis,  const float* __restrict__ Wo,
        const float* __restrict__ boutp,const float* __restrict__ Wos,
        const float* __restrict__ Wmus, const float* __restrict__ Marm,
        float* __restrict__ out, float* ws)
{
  __shared__ float sm[14336];          // 56 KB, role-specific layout
  __shared__ unsigned smDead;
  unsigned* ctrA = (unsigned*)ws + WS_CTRA;
  unsigned* ctrB = (unsigned*)ws + WS_CTRB;
  unsigned* ctrC = (unsigned*)ws + WS_CTRC;
  float* RH1 = ws + WS_RH1;
  float* RH2 = ws + WS_RH2;
  float* RIV = ws + WS_RIV;

  const int bid = blockIdx.x, tid = threadIdx.x;
  const int wave = tid >> 6, lane = tid & 63;
  const int kk = lane & 15, rr = lane >> 4;
  if (tid == 0) smDead = 0u;

  if (bid < NAg) {
    // ================= stage A : h1 rows [bid*16, +16) =================
    float* Wl   = sm;            // [16][WST]
    float* Xh   = sm + 8256;     // [BB][NHP]  staged h1_prev
    float* ivl  = sm + 12864;    // [BB][12]   staged in_vec
    float* WinL = sm + 12972;    // [16][12]
    float* binL = sm + 13164;    // [16]
    float* stg  = sm + 13180;    // [2][16][9]
    const int rowBase = bid * 16;
    for (int i = tid; i < 16*NHP; i += 256){
      int r = i >> 9, j = i & (NHP-1); int gr = rowBase + r;
      Wl[r*WST + j] = (gr < NHc && j < NHc) ? Wis[gr*NHc + j] : 0.f;
    }
    for (int i = tid; i < 16*12; i += 256){
      int r = i / 12, c = i % 12; int gr = rowBase + r;
      WinL[i] = (gr < NHc) ? Win[gr*12 + c] : 0.f;
    }
    if (tid < 16){ int gr = rowBase + tid; binL[tid] = (gr < NHc) ? binp[gr] : 0.f; }
    __syncthreads();

    for (int s = 0; s < TT; ++s){
      if (tid == 0){
        if (!smDead){
          bool ok = waitGE(ctrA, (long long)NAg * s);                       // h1_{s-1}
          long long ivt = (s == 0) ? 0 : ((s <= 6) ? 1 : (long long)(s-5)); // in_vec_s
          ok = ok && waitGE(ctrC, ivt);
          ok = ok && waitGE(ctrB, (long long)NBg * (s - 3));                // ring backpressure
          if (!ok) smDead = 1u;
        }
        __threadfence();   // acquire: invalidate caches before ring reads
      }
      __syncthreads();
      if (s == 0){
        for (int i = tid; i < BB*NHP; i += 256) Xh[i] = 0.f;
        if (tid < BB*12) ivl[tid] = 0.f;
      } else {
        const float4* src = (const float4*)(RH1 + ((s-1) & (RING-1))*BB*NHP);
        float4* dst = (float4*)Xh;
        for (int i = tid; i < BB*NHP/4; i += 256) dst[i] = src[i];
        if (tid < BB*12) ivl[tid] = RIV[(s & (IVR-1))*BB*12 + tid];
      }
      __syncthreads();

      // pre1 partials: rows (wave&1)*8 + rr*2 +{0,1}, K-half = wave>>1
      const int r0 = (wave & 1)*8 + rr*2, r1c = r0 + 1;
      const int kHalf = wave >> 1;
      float a0[9], a1[9];
      #pragma unroll
      for (int b = 0; b < 9; ++b){ a0[b] = 0.f; a1[b] = 0.f; }
      #pragma unroll
      for (int it = 0; it < 4; ++it){
        int jb = kHalf*256 + it*64 + kk*4;
        float4 w0 = *(const float4*)&Wl[r0*WST + jb];
        float4 w1 = *(const float4*)&Wl[r1c*WST + jb];
        #pragma unroll
        for (int b = 0; b < 9; ++b){
          float4 h = *(const float4*)&Xh[b*NHP + jb];
          a0[b] = fmaf(w0.x,h.x, fmaf(w0.y,h.y, fmaf(w0.z,h.z, fmaf(w0.w,h.w, a0[b]))));
          a1[b] = fmaf(w1.x,h.x, fmaf(w1.y,h.y, fmaf(w1.z,h.z, fmaf(w1.w,h.w, a1[b]))));
        }
      }
      #pragma unroll
      for (int mk = 1; mk < 16; mk <<= 1){
        #pragma unroll
        for (int b = 0; b < 9; ++b){
          a0[b] += __shfl_xor(a0[b], mk, 64);
          a1[b] += __shfl_xor(a1[b], mk, 64);
        }
      }
      if (kk < 9){
        float v0 = 0.f, v1 = 0.f;
        #pragma unroll
        for (int b = 0; b < 9; ++b){ if (kk == b){ v0 = a0[b]; v1 = a1[b]; } }
        stg[kHalf*144 + r0*9  + kk] = v0;
        stg[kHalf*144 + r1c*9 + kk] = v1;
      }
      __syncthreads();

      if (tid < 144){
        int r = tid / 9, b = tid % 9, gr = rowBase + r;
        if (gr < NHc){
          float pre = stg[r*9 + b] + stg[144 + r*9 + b] + binL[r];
          #pragma unroll
          for (int c = 0; c < 10; ++c) pre = fmaf(ivl[b*12 + c], WinL[r*12 + 2 + c], pre);
          float h;
          if (s == 0) h = tanhf(pre);                 // net_in0 == 0 -> tanh(b_in)
          else {
            float hp = Xh[b*NHP + gr];
            float nz = n1g[(size_t)(s-1)*(BB*NHc) + b*NHc + gr];
            h = 0.5f*tanhf(pre) + 0.5f*hp + nz*hp*hp;
          }
          RH1[(s & (RING-1))*BB*NHP + b*NHP + gr] = h;
        }
      }
      __syncthreads();
      if (tid == 0){
        __threadfence();   // release: publish ring slice
        __hip_atomic_fetch_add(ctrA, 1u, __ATOMIC_RELEASE, __HIP_MEMORY_SCOPE_AGENT);
      }
    }
  } else if (bid < NAg + NBg) {
    // ================= stage B : h2 rows [(bid-32)*8, +8) =================
    float* WoL  = sm;           // [8][WST]
    float* WsL  = sm + 4128;    // [8][WST]
    float* Xh   = sm + 8256;    // [BB][NHP]
    float* sv   = sm + 12864;   // [8][9] saved h2p slice
    float* stg  = sm + 12936;   // [8][8][9]
    float* boL  = sm + 13512;   // [8]
    const int rowBase = (bid - NAg) * 8;
    for (int i = tid; i < 8*NHP; i += 256){
      int r = i >> 9, j = i & (NHP-1); int gr = rowBase + r;
      WoL[r*WST + j] = (gr < NHc && j < NHc) ? Wo[gr*NHc + j]  : 0.f;
      WsL[r*WST + j] = (gr < NHc && j < NHc) ? Wos[gr*NHc + j] : 0.f;
    }
    if (tid < 8){ int gr = rowBase + tid; boL[tid] = (gr < NHc) ? boutp[gr] : 0.f; }
    __syncthreads();

    auto mm = [&](const float* M, int p){
      float a0[9], a1[9];
      #pragma unroll
      for (int b = 0; b < 9; ++b){ a0[b] = 0.f; a1[b] = 0.f; }
      const int r0 = rr*2;
      #pragma unroll
      for (int it = 0; it < 2; ++it){
        int jb = wave*128 + it*64 + kk*4;    // wave = K-quarter
        float4 w0 = *(const float4*)&M[r0*WST + jb];
        float4 w1 = *(const float4*)&M[(r0+1)*WST + jb];
        #pragma unroll
        for (int b = 0; b < 9; ++b){
          float4 h = *(const float4*)&Xh[b*NHP + jb];
          a0[b] = fmaf(w0.x,h.x, fmaf(w0.y,h.y, fmaf(w0.z,h.z, fmaf(w0.w,h.w, a0[b]))));
          a1[b] = fmaf(w1.x,h.x, fmaf(w1.y,h.y, fmaf(w1.z,h.z, fmaf(w1.w,h.w, a1[b]))));
        }
      }
      #pragma unroll
      for (int mk = 1; mk < 16; mk <<= 1){
        #pragma unroll
        for (int b = 0; b < 9; ++b){
          a0[b] += __shfl_xor(a0[b], mk, 64);
          a1[b] += __shfl_xor(a1[b], mk, 64);
        }
      }
      if (kk < 9){
        float v0 = 0.f, v1 = 0.f;
        #pragma unroll
        for (int b = 0; b < 9; ++b){ if (kk == b){ v0 = a0[b]; v1 = a1[b]; } }
        stg[(p*4 + wave)*72 + r0*9     + kk] = v0;
        stg[(p*4 + wave)*72 + (r0+1)*9 + kk] = v1;
      }
    };

    for (int s = 0; s < TT; ++s){
      if (tid == 0){
        if (!smDead){
          bool ok = waitGE(ctrB, (long long)NBg * s);        // h2_{s-1}
          ok = ok && waitGE(ctrC, (long long)(s - 3));       // ring backpressure
          if (!ok) smDead = 1u;
        }
        __threadfence();
      }
      __syncthreads();
      if (s == 0){
        for (int i = tid; i < BB*NHP; i += 256) Xh[i] = 0.f;
      } else {
        const float4* src = (const float4*)(RH2 + ((s-1) & (RING-1))*BB*NHP);
        float4* dst = (float4*)Xh;
        for (int i = tid; i < BB*NHP/4; i += 256) dst[i] = src[i];
      }
      __syncthreads();
      if (tid < 72){
        int r = tid / 9, b = tid % 9, gr = rowBase + r;
        sv[tid] = (gr < NHc) ? Xh[b*NHP + gr] : 0.f;
      }
      mm(WsL, 0);                          // W_out_self x h2p (hides wait for h1_s)
      __syncthreads();
      if (tid == 0){
        if (!smDead){ if (!waitGE(ctrA, (long long)NAg * (s + 1))) smDead = 1u; }  // h1_s
        __threadfence();
      }
      __syncthreads();
      {
        const float4* src = (const float4*)(RH1 + (s & (RING-1))*BB*NHP);
        float4* dst = (float4*)Xh;
        for (int i = tid; i < BB*NHP/4; i += 256) dst[i] = src[i];
      }
      __syncthreads();
      mm(WoL, 1);                          // W_out x h1_s
      __syncthreads();
      if (tid < 72){
        int r = tid / 9, b = tid % 9, gr = rowBase + r;
        if (gr < NHc){
          float pre = boL[r];
          #pragma unroll
          for (int pq = 0; pq < 8; ++pq) pre += stg[pq*72 + r*9 + b];
          float h;
          if (s == 0) h = tanhf(pre);
          else {
            float hp = sv[tid];
            float nz = n2g[(size_t)(s-1)*(BB*NHc) + b*NHc + gr];
            h = 0.5f*tanhf(pre) + 0.5f*hp + nz*hp*hp;
          }
          RH2[(s & (RING-1))*BB*NHP + b*NHP + gr] = h;
        }
      }
      __syncthreads();
      if (tid == 0){
        __threadfence();
        __hip_atomic_fetch_add(ctrB, 1u, __ATOMIC_RELEASE, __HIP_MEMORY_SCOPE_AGENT);
      }
    }
  } else {
    // ========== stage C : muscles + joints + output + in_vec (6 steps ahead) ==========
    float* WmL  = sm;            // [6][WST]
    float* Xh   = sm + 3096;     // [BB][NHP]
    float* stg  = sm + 7704;     // [4][6][9]
    float* mst  = sm + 7920;     // [BB][6]
    float* js   = sm + 7974;     // [BB][4]
    float* MaL  = sm + 8010;     // [6][2]
    float* hoL  = sm + 8022;     // [BB][2]
    for (int i = tid; i < 6*NHP; i += 256){
      int r = i >> 9, j = i & (NHP-1);
      WmL[r*WST + j] = (j < NHc) ? Wmus[r*NHc + j] : 0.f;
    }
    if (tid < 12) MaL[tid] = Marm[tid];
    if (tid < 18) hoL[tid] = homeg[tid];
    __syncthreads();

    for (int s = 0; s < TT; ++s){
      if (tid == 0){
        if (!smDead){ if (!waitGE(ctrB, (long long)NBg * (s + 1))) smDead = 1u; }  // h2_s
        __threadfence();
      }
      __syncthreads();
      {
        const float4* src = (const float4*)(RH2 + (s & (RING-1))*BB*NHP);
        float4* dst = (float4*)Xh;
        for (int i = tid; i < BB*NHP/4; i += 256) dst[i] = src[i];
      }
      __syncthreads();
      {
        float a0[9], a1[9];
        #pragma unroll
        for (int b = 0; b < 9; ++b){ a0[b] = 0.f; a1[b] = 0.f; }
        const int r0 = (rr < 3 ? rr : 0) * 2;
        #pragma unroll
        for (int it = 0; it < 2; ++it){
          int jb = wave*128 + it*64 + kk*4;
          float4 w0 = *(const float4*)&WmL[r0*WST + jb];
          float4 w1 = *(const float4*)&WmL[(r0+1)*WST + jb];
          #pragma unroll
          for (int b = 0; b < 9; ++b){
            float4 h = *(const float4*)&Xh[b*NHP + jb];
            a0[b] = fmaf(w0.x,h.x, fmaf(w0.y,h.y, fmaf(w0.z,h.z, fmaf(w0.w,h.w, a0[b]))));
            a1[b] = fmaf(w1.x,h.x, fmaf(w1.y,h.y, fmaf(w1.z,h.z, fmaf(w1.w,h.w, a1[b]))));
          }
        }
        #pragma unroll
        for (int mk = 1; mk < 16; mk <<= 1){
          #pragma unroll
          for (int b = 0; b < 9; ++b){
            a0[b] += __shfl_xor(a0[b], mk, 64);
            a1[b] += __shfl_xor(a1[b], mk, 64);
          }
        }
        if (kk < 9 && rr < 3){
          float v0 = 0.f, v1 = 0.f;
          #pragma unroll
          for (int b = 0; b < 9; ++b){ if (kk == b){ v0 = a0[b]; v1 = a1[b]; } }
          stg[wave*54 + (rr*2)*9   + kk] = v0;
          stg[wave*54 + (rr*2+1)*9 + kk] = v1;
        }
      }
      __syncthreads();
      if (tid < 54){
        int u = tid / 9, b = tid % 9;
        float pre = stg[u*9+b] + stg[54 + u*9+b] + stg[108 + u*9+b] + stg[162 + u*9+b];
        float rel = fmaxf(pre, 0.f);
        float mn;
        if (s == 0) mn = rel;
        else {
          float mp = mst[b*6 + u];
          float nz = nmg[(size_t)(s-1)*(BB*NMc) + b*NMc + u];
          mn = 0.2f*rel + 0.8f*mp + nz*mp*mp;
        }
        mst[b*6 + u] = mn;
      }
      __syncthreads();
      if (s == 0){
        if (tid < 18){
          int b = tid >> 1, c = tid & 1;
          js[b*4 + c] = hoL[b*2 + c];
          js[b*4 + 2 + c] = 0.f;
          out[b*4 + c] = hoL[b*2 + c];
          out[b*4 + 2 + c] = 0.f;
        }
      } else {
        if (tid < 18){
          int b = tid >> 1, c = tid & 1;
          float tq = 0.f;
          #pragma unroll
          for (int u = 0; u < 6; ++u) tq = fmaf(mst[b*6 + u], MaL[u*2 + c], tq);
          tq += pert[(size_t)(s-1)*(BB*2) + b*2 + c];
          float v  = js[b*4 + 2 + c] + 0.01f * tq;
          float pn = js[b*4 + c] + 0.01f * v;
          js[b*4 + c] = pn;
          js[b*4 + 2 + c] = v;
          out[(size_t)s*(BB*4) + b*4 + c]     = pn;
          out[(size_t)s*(BB*4) + b*4 + 2 + c] = v;
        }
      }
      __syncthreads();
      if (tid < BB*12){   // publish in_vec_{s+6} (state s is exactly what it needs)
        int b = tid / 12, k = tid % 12;
        float val;
        if (k < 2)       val = 2.f * (js[b*4 + k] - hoL[b*2 + k]);
        else if (k < 4)  val = 0.5f * js[b*4 + 2 + (k - 2)];
        else if (k < 10) val = mst[b*6 + (k - 4)];
        else             val = 0.f;
        if (s == 0){
          #pragma unroll
          for (int q = 1; q <= 6; ++q) RIV[q*(BB*12) + tid] = val;
        } else {
          RIV[((s + 6) & (IVR-1))*(BB*12) + tid] = val;
        }
      }
      __syncthreads();
      if (tid == 0){
        __threadfence();
        __hip_atomic_fetch_add(ctrC, 1u, __ATOMIC_RELEASE, __HIP_MEMORY_SCOPE_AGENT);
      }
    }
  }
}

extern "C" void kernel_launch(void* const* d_in, const int* in_sizes, int n_in,
                              void* d_out, int out_size, void* d_ws, size_t ws_size,
                              hipStream_t stream) {
  // input order: 0 des(unused) 1 pert 2 n1 3 n2 4 nm 5 home 6 W_in 7 b_in
  //              8 W_in_self 9 W_out 10 b_out 11 W_out_self 12 W_mus 13 M_arm
  const float* pert = (const float*)d_in[1];
  const float* n1   = (const float*)d_in[2];
  const float* n2   = (const float*)d_in[3];
  const float* nm   = (const float*)d_in[4];
  const float* home = (const float*)d_in[5];
  const float* Win  = (const float*)d_in[6];
  const float* bin  = (const float*)d_in[7];
  const float* Wis  = (const float*)d_in[8];
  const float* Wo   = (const float*)d_in[9];
  const float* bout = (const float*)d_in[10];
  const float* Wos  = (const float*)d_in[11];
  const float* Wmus = (const float*)d_in[12];
  const float* Marm = (const float*)d_in[13];
  (void)in_sizes; (void)n_in; (void)out_size; (void)ws_size; // needs ~155 KB of ws

  // reset sync counters every launch (graph-capturable memset node)
  hipMemsetAsync(d_ws, 0, 512, stream);
  hipLaunchKernelGGL(fb_pipe, dim3(NAg + NBg + 1), dim3(256), 0, stream,
                     pert, n1, n2, nm, home, Win, bin, Wis, Wo, bout, Wos,
                     Wmus, Marm, (float*)d_out, (float*)d_ws);
}

// Round 6
// 48759.589 us; speedup vs baseline: 1.1945x; 1.1945x over previous
//
#include <hip/hip_runtime.h>
#include <math.h>

// ---------------- problem constants ----------------
#define TT   4096
#define BB   9
#define NHc  500
#define NHP  512          // padded hidden dim
#define NMc  6
// ---------------- grid roles ----------------
#define NAg  32           // stage-A WGs (h1), 16 rows each
#define NBg  63           // stage-B WGs (h2), 8 rows each
#define RGD  8            // h1/h2 ring depth
#define IVR  16           // in_vec ring depth
#define WST  516          // LDS weight row stride (bank spread)

// ws layout (float index). Flags are ints in ws[0..4095]:
//   FA[i] at 32*i (i<32); FB[j] at 1024+32*j (j<63); FC at 3040. 128B padding.
#define WS_RH1   4096
#define WS_RH2   (WS_RH1 + RGD*BB*NHP)
#define WS_RIV   (WS_RH2 + RGD*BB*NHP)   // + IVR*BB*12 -> 79552 floats (~318 KB)

// R1-proven sync semantics: poll relaxed-agent atomic load (+s_sleep backoff);
// acquire = tid0 __threadfence() AFTER polls, BEFORE plain-load reads;
// release = plain stores -> __syncthreads -> tid0 __threadfence() + RELEASE add.
__device__ __forceinline__ bool waitFlag(const int* p, int tgt){
  if (tgt <= 0) return true;
  long long n = 0;
  while (__hip_atomic_load(p, __ATOMIC_RELAXED, __HIP_MEMORY_SCOPE_AGENT) < tgt){
    __builtin_amdgcn_s_sleep(2);
    if (++n > (1LL<<20)) return false;   // safety: wrong answer instead of hang
  }
  return true;
}

extern "C" __global__ void __launch_bounds__(256)
fb_pipe(const float* __restrict__ pert,
        const float* __restrict__ n1g, const float* __restrict__ n2g,
        const float* __restrict__ nmg, const float* __restrict__ homeg,
        const float* __restrict__ Win,  const float* __restrict__ binp,
        const float* __restrict__ Wis,  const float* __restrict__ Wo,
        const float* __restrict__ boutp,const float* __restrict__ Wos,
        const float* __restrict__ Wmus, const float* __restrict__ Marm,
        float* __restrict__ out, float* ws)
{
  __shared__ float sm[14336];          // 56 KB, role-specific layout
  __shared__ unsigned smDead;
  int* FLG = (int*)ws;
  float* RH1 = ws + WS_RH1;
  float* RH2 = ws + WS_RH2;
  float* RIV = ws + WS_RIV;

  const int bid = blockIdx.x, tid = threadIdx.x;
  const int wave = tid >> 6, lane = tid & 63;
  const int kk = lane & 15, rr = lane >> 4;
  if (tid == 0) smDead = 0u;

  if (bid < NAg) {
    // ================= stage A : h1 rows [bid*16, +16) =================
    float* Wl   = sm;            // [16][WST]
    float* Xh   = sm + 8256;     // [BB][NHP]  staged h1_prev
    float* ivl  = sm + 12864;    // [BB][12]   staged in_vec
    float* WinL = sm + 12972;    // [16][12]
    float* binL = sm + 13164;    // [16]
    float* stg  = sm + 13180;    // [2][16][9]
    const int rowBase = bid * 16;
    int* myF = &FLG[bid*32];
    for (int i = tid; i < 16*NHP; i += 256){
      int r = i >> 9, j = i & (NHP-1); int gr = rowBase + r;
      Wl[r*WST + j] = (gr < NHc && j < NHc) ? Wis[gr*NHc + j] : 0.f;
    }
    for (int i = tid; i < 16*12; i += 256){
      int r = i / 12, c = i % 12; int gr = rowBase + r;
      WinL[i] = (gr < NHc) ? Win[gr*12 + c] : 0.f;
    }
    if (tid < 16){ int gr = rowBase + tid; binL[tid] = (gr < NHc) ? binp[gr] : 0.f; }
    __syncthreads();

    for (int s = 0; s < TT; ++s){
      // --- prefetch noise (immutable input; hides under poll) ---
      const int fr = tid / 9, fb = tid % 9;
      float nz = 0.f;
      if (s > 0 && tid < 144){
        int gr = rowBase + fr;
        if (gr < NHc) nz = n1g[(size_t)(s-1)*(BB*NHc) + fb*NHc + gr];
      }
      // --- polls: wave0 = read-gates (A peers + C's in_vec); wave1 = B backpressure ---
      if (!smDead){
        bool ok = true;
        if (wave == 0){
          if (lane < NAg)       ok = waitFlag(&FLG[lane*32], s);
          else if (lane == 63){ int t = (s == 0) ? 0 : ((s <= 6) ? 1 : (s - 5));
                                ok = waitFlag(&FLG[3040], t); }
        } else if (wave == 1 && lane < NBg){
          if (s > RGD-1) ok = waitFlag(&FLG[1024 + lane*32], s - (RGD-1));
        }
        if (!ok) smDead = 1u;
      }
      if (tid == 0) __threadfence();     // acquire (after wave0 polls, same-wave order)
      __syncthreads();
      // --- fetch h1_{s-1} + in_vec_s (plain loads; fence invalidated caches) ---
      if (s == 0){
        for (int i = tid; i < BB*NHP; i += 256) Xh[i] = 0.f;
        if (tid < BB*12) ivl[tid] = 0.f;
      } else {
        const float4* src = (const float4*)(RH1 + ((s-1) & (RGD-1))*BB*NHP);
        float4* dst = (float4*)Xh;
        for (int i = tid; i < BB*NHP/4; i += 256) dst[i] = src[i];
        if (tid < BB*12) ivl[tid] = RIV[(s & (IVR-1))*BB*12 + tid];
      }
      __syncthreads();

      // --- pre1 partials: rows (wave&1)*8 + rr*2 +{0,1}, K-half = wave>>1 ---
      const int r0 = (wave & 1)*8 + rr*2, r1c = r0 + 1;
      const int kHalf = wave >> 1;
      float a0[9], a1[9];
      #pragma unroll
      for (int b = 0; b < 9; ++b){ a0[b] = 0.f; a1[b] = 0.f; }
      #pragma unroll
      for (int it = 0; it < 4; ++it){
        int jb = kHalf*256 + it*64 + kk*4;
        float4 w0 = *(const float4*)&Wl[r0*WST + jb];
        float4 w1 = *(const float4*)&Wl[r1c*WST + jb];
        #pragma unroll
        for (int b = 0; b < 9; ++b){
          float4 h = *(const float4*)&Xh[b*NHP + jb];
          a0[b] = fmaf(w0.x,h.x, fmaf(w0.y,h.y, fmaf(w0.z,h.z, fmaf(w0.w,h.w, a0[b]))));
          a1[b] = fmaf(w1.x,h.x, fmaf(w1.y,h.y, fmaf(w1.z,h.z, fmaf(w1.w,h.w, a1[b]))));
        }
      }
      #pragma unroll
      for (int mk = 1; mk < 16; mk <<= 1){
        #pragma unroll
        for (int b = 0; b < 9; ++b){
          a0[b] += __shfl_xor(a0[b], mk, 64);
          a1[b] += __shfl_xor(a1[b], mk, 64);
        }
      }
      if (kk < 9){
        float v0 = 0.f, v1 = 0.f;
        #pragma unroll
        for (int b = 0; b < 9; ++b){ if (kk == b){ v0 = a0[b]; v1 = a1[b]; } }
        stg[kHalf*144 + r0*9  + kk] = v0;
        stg[kHalf*144 + r1c*9 + kk] = v1;
      }
      __syncthreads();

      if (tid < 144){
        int gr = rowBase + fr;
        if (gr < NHc){
          float pre = stg[fr*9 + fb] + stg[144 + fr*9 + fb] + binL[fr];
          #pragma unroll
          for (int c = 0; c < 10; ++c) pre = fmaf(ivl[fb*12 + c], WinL[fr*12 + 2 + c], pre);
          float h;
          if (s == 0) h = tanhf(pre);
          else {
            float hp = Xh[fb*NHP + gr];
            h = 0.5f*tanhf(pre) + 0.5f*hp + nz*hp*hp;
          }
          RH1[(s & (RGD-1))*BB*NHP + fb*NHP + gr] = h;   // plain store
        }
      }
      __syncthreads();
      if (tid == 0){
        __threadfence();                                   // release
        __hip_atomic_fetch_add(myF, 1, __ATOMIC_RELEASE, __HIP_MEMORY_SCOPE_AGENT);
      }
    }
  } else if (bid < NAg + NBg) {
    // ================= stage B : h2 rows [(bid-32)*8, +8) =================
    float* WoL  = sm;           // [8][WST]
    float* WsL  = sm + 4128;    // [8][WST]
    float* Xh   = sm + 8256;    // [BB][NHP]
    float* sv   = sm + 12864;   // [8][9] saved h2p slice
    float* stg  = sm + 12936;   // [8][8][9]
    float* boL  = sm + 13512;   // [8]
    const int rowBase = (bid - NAg) * 8;
    int* myF = &FLG[1024 + (bid - NAg)*32];
    for (int i = tid; i < 8*NHP; i += 256){
      int r = i >> 9, j = i & (NHP-1); int gr = rowBase + r;
      WoL[r*WST + j] = (gr < NHc && j < NHc) ? Wo[gr*NHc + j]  : 0.f;
      WsL[r*WST + j] = (gr < NHc && j < NHc) ? Wos[gr*NHc + j] : 0.f;
    }
    if (tid < 8){ int gr = rowBase + tid; boL[tid] = (gr < NHc) ? boutp[gr] : 0.f; }
    __syncthreads();

    auto mm = [&](const float* M, int p){
      float a0[9], a1[9];
      #pragma unroll
      for (int b = 0; b < 9; ++b){ a0[b] = 0.f; a1[b] = 0.f; }
      const int r0 = rr*2;
      #pragma unroll
      for (int it = 0; it < 2; ++it){
        int jb = wave*128 + it*64 + kk*4;    // wave = K-quarter
        float4 w0 = *(const float4*)&M[r0*WST + jb];
        float4 w1 = *(const float4*)&M[(r0+1)*WST + jb];
        #pragma unroll
        for (int b = 0; b < 9; ++b){
          float4 h = *(const float4*)&Xh[b*NHP + jb];
          a0[b] = fmaf(w0.x,h.x, fmaf(w0.y,h.y, fmaf(w0.z,h.z, fmaf(w0.w,h.w, a0[b]))));
          a1[b] = fmaf(w1.x,h.x, fmaf(w1.y,h.y, fmaf(w1.z,h.z, fmaf(w1.w,h.w, a1[b]))));
        }
      }
      #pragma unroll
      for (int mk = 1; mk < 16; mk <<= 1){
        #pragma unroll
        for (int b = 0; b < 9; ++b){
          a0[b] += __shfl_xor(a0[b], mk, 64);
          a1[b] += __shfl_xor(a1[b], mk, 64);
        }
      }
      if (kk < 9){
        float v0 = 0.f, v1 = 0.f;
        #pragma unroll
        for (int b = 0; b < 9; ++b){ if (kk == b){ v0 = a0[b]; v1 = a1[b]; } }
        stg[(p*4 + wave)*72 + r0*9     + kk] = v0;
        stg[(p*4 + wave)*72 + (r0+1)*9 + kk] = v1;
      }
    };

    for (int s = 0; s < TT; ++s){
      const int fr = tid / 9, fb = tid % 9;
      float nz = 0.f;
      if (s > 0 && tid < 72){
        int gr = rowBase + fr;
        if (gr < NHc) nz = n2g[(size_t)(s-1)*(BB*NHc) + fb*NHc + gr];
      }
      // --- top polls: peers h2_{s-1} (read gate) + C backpressure (write gate) ---
      if (!smDead){
        bool ok = true;
        if (wave == 0 && lane < NBg)             ok = waitFlag(&FLG[1024 + lane*32], s);
        else if (wave == 1 && lane == 0){ if (s > RGD-1) ok = waitFlag(&FLG[3040], s - (RGD-1)); }
        if (!ok) smDead = 1u;
      }
      if (tid == 0) __threadfence();     // acquire
      __syncthreads();
      if (s == 0){
        for (int i = tid; i < BB*NHP; i += 256) Xh[i] = 0.f;
      } else {
        const float4* src = (const float4*)(RH2 + ((s-1) & (RGD-1))*BB*NHP);
        float4* dst = (float4*)Xh;
        for (int i = tid; i < BB*NHP/4; i += 256) dst[i] = src[i];
      }
      __syncthreads();
      if (tid < 72){
        int gr = rowBase + fr;
        sv[tid] = (gr < NHc) ? Xh[fb*NHP + gr] : 0.f;
      }
      mm(WsL, 0);                          // self part (zeros at s==0 since Xh=0)
      __syncthreads();
      // --- mid poll: h1_s ready (A runs ahead; usually satisfied) ---
      if (!smDead && wave == 0 && lane < NAg){
        if (!waitFlag(&FLG[lane*32], s + 1)) smDead = 1u;
      }
      if (tid == 0) __threadfence();     // acquire
      __syncthreads();
      {
        const float4* src = (const float4*)(RH1 + (s & (RGD-1))*BB*NHP);
        float4* dst = (float4*)Xh;
        for (int i = tid; i < BB*NHP/4; i += 256) dst[i] = src[i];
      }
      __syncthreads();
      mm(WoL, 1);
      __syncthreads();
      if (tid < 72){
        int gr = rowBase + fr;
        if (gr < NHc){
          float pre = boL[fr];
          #pragma unroll
          for (int pq = 0; pq < 8; ++pq) pre += stg[pq*72 + fr*9 + fb];
          float h;
          if (s == 0) h = tanhf(pre);
          else {
            float hp = sv[tid];
            h = 0.5f*tanhf(pre) + 0.5f*hp + nz*hp*hp;
          }
          RH2[(s & (RGD-1))*BB*NHP + fb*NHP + gr] = h;   // plain store
        }
      }
      __syncthreads();
      if (tid == 0){
        __threadfence();                                   // release
        __hip_atomic_fetch_add(myF, 1, __ATOMIC_RELEASE, __HIP_MEMORY_SCOPE_AGENT);
      }
    }
  } else {
    // ========== stage C : muscles + joints + output + in_vec (6 steps ahead) ==========
    float* WmL  = sm;            // [6][WST]
    float* Xh   = sm + 3096;     // [BB][NHP]
    float* stg  = sm + 7704;     // [4][6][9]
    float* mst  = sm + 7920;     // [BB][6]
    float* js   = sm + 7974;     // [BB][4]
    float* MaL  = sm + 8010;     // [6][2]
    float* hoL  = sm + 8022;     // [BB][2]
    int* myF = &FLG[3040];
    for (int i = tid; i < 6*NHP; i += 256){
      int r = i >> 9, j = i & (NHP-1);
      WmL[r*WST + j] = (j < NHc) ? Wmus[r*NHc + j] : 0.f;
    }
    if (tid < 12) MaL[tid] = Marm[tid];
    if (tid < 18) hoL[tid] = homeg[tid];
    __syncthreads();

    for (int s = 0; s < TT; ++s){
      float nz = 0.f, pv = 0.f;
      if (s > 0 && tid < 54){
        int u = tid / 9, b = tid % 9;
        nz = nmg[(size_t)(s-1)*(BB*NMc) + b*NMc + u];
      }
      if (s > 0 && tid < 18) pv = pert[(size_t)(s-1)*(BB*2) + tid];
      if (!smDead){
        bool ok = true;
        if (wave == 0 && lane < NBg) ok = waitFlag(&FLG[1024 + lane*32], s + 1);
        if (!ok) smDead = 1u;
      }
      if (tid == 0) __threadfence();     // acquire
      __syncthreads();
      {
        const float4* src = (const float4*)(RH2 + (s & (RGD-1))*BB*NHP);
        float4* dst = (float4*)Xh;
        for (int i = tid; i < BB*NHP/4; i += 256) dst[i] = src[i];
      }
      __syncthreads();
      {
        float a0[9], a1[9];
        #pragma unroll
        for (int b = 0; b < 9; ++b){ a0[b] = 0.f; a1[b] = 0.f; }
        const int r0 = (rr < 3 ? rr : 0) * 2;
        #pragma unroll
        for (int it = 0; it < 2; ++it){
          int jb = wave*128 + it*64 + kk*4;
          float4 w0 = *(const float4*)&WmL[r0*WST + jb];
          float4 w1 = *(const float4*)&WmL[(r0+1)*WST + jb];
          #pragma unroll
          for (int b = 0; b < 9; ++b){
            float4 h = *(const float4*)&Xh[b*NHP + jb];
            a0[b] = fmaf(w0.x,h.x, fmaf(w0.y,h.y, fmaf(w0.z,h.z, fmaf(w0.w,h.w, a0[b]))));
            a1[b] = fmaf(w1.x,h.x, fmaf(w1.y,h.y, fmaf(w1.z,h.z, fmaf(w1.w,h.w, a1[b]))));
          }
        }
        #pragma unroll
        for (int mk = 1; mk < 16; mk <<= 1){
          #pragma unroll
          for (int b = 0; b < 9; ++b){
            a0[b] += __shfl_xor(a0[b], mk, 64);
            a1[b] += __shfl_xor(a1[b], mk, 64);
          }
        }
        if (kk < 9 && rr < 3){
          float v0 = 0.f, v1 = 0.f;
          #pragma unroll
          for (int b = 0; b < 9; ++b){ if (kk == b){ v0 = a0[b]; v1 = a1[b]; } }
          stg[wave*54 + (rr*2)*9   + kk] = v0;
          stg[wave*54 + (rr*2+1)*9 + kk] = v1;
        }
      }
      __syncthreads();
      if (tid < 54){
        int u = tid / 9, b = tid % 9;
        float pre = stg[u*9+b] + stg[54 + u*9+b] + stg[108 + u*9+b] + stg[162 + u*9+b];
        float rel = fmaxf(pre, 0.f);
        float mn;
        if (s == 0) mn = rel;
        else {
          float mp = mst[b*6 + u];
          mn = 0.2f*rel + 0.8f*mp + nz*mp*mp;
        }
        mst[b*6 + u] = mn;
      }
      __syncthreads();
      if (s == 0){
        if (tid < 18){
          int b = tid >> 1, c = tid & 1;
          js[b*4 + c] = hoL[b*2 + c];
          js[b*4 + 2 + c] = 0.f;
          out[b*4 + c] = hoL[b*2 + c];
          out[b*4 + 2 + c] = 0.f;
        }
      } else {
        if (tid < 18){
          int b = tid >> 1, c = tid & 1;
          float tq = 0.f;
          #pragma unroll
          for (int u = 0; u < 6; ++u) tq = fmaf(mst[b*6 + u], MaL[u*2 + c], tq);
          tq += pv;
          float v  = js[b*4 + 2 + c] + 0.01f * tq;
          float pn = js[b*4 + c] + 0.01f * v;
          js[b*4 + c] = pn;
          js[b*4 + 2 + c] = v;
          out[(size_t)s*(BB*4) + b*4 + c]     = pn;
          out[(size_t)s*(BB*4) + b*4 + 2 + c] = v;
        }
      }
      __syncthreads();
      if (tid < BB*12){   // publish in_vec_{s+6}
        int b = tid / 12, k = tid % 12;
        float val;
        if (k < 2)       val = 2.f * (js[b*4 + k] - hoL[b*2 + k]);
        else if (k < 4)  val = 0.5f * js[b*4 + 2 + (k - 2)];
        else if (k < 10) val = mst[b*6 + (k - 4)];
        else             val = 0.f;
        if (s == 0){
          #pragma unroll
          for (int q = 1; q <= 6; ++q) RIV[q*(BB*12) + tid] = val;
        } else {
          RIV[((s + 6) & (IVR-1))*(BB*12) + tid] = val;
        }
      }
      __syncthreads();
      if (tid == 0){
        __threadfence();                                   // release
        __hip_atomic_fetch_add(myF, 1, __ATOMIC_RELEASE, __HIP_MEMORY_SCOPE_AGENT);
      }
    }
  }
}

extern "C" void kernel_launch(void* const* d_in, const int* in_sizes, int n_in,
                              void* d_out, int out_size, void* d_ws, size_t ws_size,
                              hipStream_t stream) {
  // input order: 0 des(unused) 1 pert 2 n1 3 n2 4 nm 5 home 6 W_in 7 b_in
  //              8 W_in_self 9 W_out 10 b_out 11 W_out_self 12 W_mus 13 M_arm
  const float* pert = (const float*)d_in[1];
  const float* n1   = (const float*)d_in[2];
  const float* n2   = (const float*)d_in[3];
  const float* nm   = (const float*)d_in[4];
  const float* home = (const float*)d_in[5];
  const float* Win  = (const float*)d_in[6];
  const float* bin  = (const float*)d_in[7];
  const float* Wis  = (const float*)d_in[8];
  const float* Wo   = (const float*)d_in[9];
  const float* bout = (const float*)d_in[10];
  const float* Wos  = (const float*)d_in[11];
  const float* Wmus = (const float*)d_in[12];
  const float* Marm = (const float*)d_in[13];
  (void)in_sizes; (void)n_in; (void)out_size; (void)ws_size; // needs ~318 KB ws

  // reset per-producer flags every launch (graph-capturable memset node)
  hipMemsetAsync(d_ws, 0, 16384, stream);
  hipLaunchKernelGGL(fb_pipe, dim3(NAg + NBg + 1), dim3(256), 0, stream,
                     pert, n1, n2, nm, home, Win, bin, Wis, Wo, bout, Wos,
                     Wmus, Marm, (float*)d_out, (float*)d_ws);
}

// Round 8
// 35149.237 us; speedup vs baseline: 1.6570x; 1.3872x over previous
//
#include <hip/hip_runtime.h>
#include <math.h>

// ---------------- problem constants ----------------
#define TT   4096
#define BB   9
#define NHc  500
#define NHP  512
#define NMc  6
// ---------------- grid roles ----------------
#define NAg  8      // A blocks: 64 h1 rows each, W_in_self in REGISTERS
#define NBg  16     // B blocks: 32 h2 rows each, W_out + W_out_self in REGISTERS
#define RGD  8      // h ring depth
#define IVR  16     // in_vec ring depth

// ws ints: FA[i]=32*i (i<8); FB[j]=1024+32*j (j<16); FC=3040 (128B-padded lines)
#define WS_RH1 4096
#define WS_RH2 (WS_RH1 + RGD*BB*NHP)     // 40960
#define WS_RIV (WS_RH2 + RGD*BB*NHP)     // 77824 (+16*108 -> ~318KB)

// R1/R6-proven sync semantics (unchanged): relaxed poll + s_sleep backoff;
// acquire = tid0 __threadfence AFTER polls; release = stores -> barrier ->
// tid0 __threadfence + RELEASE fetch_add.
__device__ __forceinline__ bool waitFlag(const int* p, int tgt){
  if (tgt <= 0) return true;
  long long n = 0;
  while (__hip_atomic_load(p, __ATOMIC_RELAXED, __HIP_MEMORY_SCOPE_AGENT) < tgt){
    __builtin_amdgcn_s_sleep(2);
    if (++n > (1LL<<20)) return false;   // safety: wrong answer instead of hang
  }
  return true;
}

extern "C" __global__ void __launch_bounds__(256, 1)
fb_pipe(const float* __restrict__ pert,
        const float* __restrict__ n1g, const float* __restrict__ n2g,
        const float* __restrict__ nmg, const float* __restrict__ homeg,
        const float* __restrict__ Win,  const float* __restrict__ binp,
        const float* __restrict__ Wis,  const float* __restrict__ Wo,
        const float* __restrict__ boutp,const float* __restrict__ Wos,
        const float* __restrict__ Wmus, const float* __restrict__ Marm,
        float* __restrict__ out, float* ws)
{
  __shared__ float sm[8192];           // 32 KB, role-specific layout
  __shared__ unsigned smDead;
  int* FLG = (int*)ws;
  float* RH1 = ws + WS_RH1;
  float* RH2 = ws + WS_RH2;
  float* RIV = ws + WS_RIV;

  const int bid = blockIdx.x, tid = threadIdx.x;
  const int wave = tid >> 6, lane = tid & 63;
  const int kk = lane & 15, rr = lane >> 4;
  if (tid == 0) smDead = 0u;

  if (bid < NAg) {
    // ======== stage A : h1 rows [bid*64, +64), weights in registers ========
    float* Xh   = sm;            // [BB][NHP]
    float* ivl  = sm + 4608;     // [BB][12]
    float* WinL = sm + 4716;     // [64][12]
    float* binL = sm + 5484;     // [64]
    float* stg  = sm + 5548;     // [64][9]
    const int rowBase = bid * 64;
    int* myF = &FLG[bid*32];
    const int wr = wave*16 + rr*4;       // 4 rows per thread
    float4 wreg[4][8];
    for (int q = 0; q < 4; ++q){
      int gr = rowBase + wr + q;
      for (int it = 0; it < 8; ++it){
        int jb = it*64 + kk*4;
        float4 v = {0.f,0.f,0.f,0.f};
        if (gr < NHc && jb < NHc) v = *(const float4*)&Wis[gr*NHc + jb];
        wreg[q][it] = v;
      }
    }
    for (int i = tid; i < 64*12; i += 256){
      int r = i/12, c = i%12; int gr = rowBase + r;
      WinL[i] = (gr < NHc) ? Win[gr*12 + c] : 0.f;
    }
    if (tid < 64){ int gr = rowBase + tid; binL[tid] = (gr < NHc) ? binp[gr] : 0.f; }
    __syncthreads();

    for (int s = 0; s < TT; ++s){
      // noise prefetch (576 = 9*64 values, 3 chunks)
      float nz0=0.f, nz1=0.f, nz2=0.f;
      if (s > 0){
        { int i=tid,     b=i>>6, r=i&63, gr=rowBase+r; if (gr<NHc) nz0=n1g[(size_t)(s-1)*4500 + b*500 + gr]; }
        { int i=tid+256, b=i>>6, r=i&63, gr=rowBase+r; if (gr<NHc) nz1=n1g[(size_t)(s-1)*4500 + b*500 + gr]; }
        if (tid < 64){ int i=tid+512, b=i>>6, r=i&63, gr=rowBase+r; if (gr<NHc) nz2=n1g[(size_t)(s-1)*4500 + b*500 + gr]; }
      }
      // polls: wave0 = read gates (A peers + C in_vec); wave1 = B backpressure
      if (!smDead){
        bool ok = true;
        if (wave == 0){
          if (lane < NAg)        ok = waitFlag(&FLG[lane*32], s);
          else if (lane == 10){ int t=(s==0)?0:((s<=6)?1:(s-5)); ok = waitFlag(&FLG[3040], t); }
        } else if (wave == 1 && lane < NBg){
          if (s >= RGD) ok = waitFlag(&FLG[1024 + lane*32], s - (RGD-1));
        }
        if (!ok) smDead = 1u;
      }
      if (tid == 0) __threadfence();     // acquire
      __syncthreads();
      if (s == 0){
        for (int i = tid; i < BB*NHP; i += 256) Xh[i] = 0.f;
        if (tid < 108) ivl[tid] = 0.f;
      } else {
        const float4* src = (const float4*)(RH1 + ((s-1)&7)*4608);
        float4* dst = (float4*)Xh;
        for (int i = tid; i < 1152; i += 256) dst[i] = src[i];
        if (tid < 108) ivl[tid] = RIV[(s&15)*108 + tid];
      }
      __syncthreads();

      float acc[4][9];
      for (int q = 0; q < 4; ++q)
        for (int b = 0; b < 9; ++b) acc[q][b] = 0.f;
      #pragma unroll
      for (int it = 0; it < 8; ++it){
        int jb = it*64 + kk*4;
        #pragma unroll
        for (int b = 0; b < 9; ++b){
          float4 h = *(const float4*)&Xh[b*NHP + jb];
          #pragma unroll
          for (int q = 0; q < 4; ++q)
            acc[q][b] = fmaf(wreg[q][it].x,h.x, fmaf(wreg[q][it].y,h.y,
                        fmaf(wreg[q][it].z,h.z, fmaf(wreg[q][it].w,h.w, acc[q][b]))));
        }
      }
      #pragma unroll
      for (int mk = 1; mk < 16; mk <<= 1)
        #pragma unroll
        for (int q = 0; q < 4; ++q)
          #pragma unroll
          for (int b = 0; b < 9; ++b)
            acc[q][b] += __shfl_xor(acc[q][b], mk, 64);
      if (kk < 9){
        #pragma unroll
        for (int q = 0; q < 4; ++q){
          float v = 0.f;
          #pragma unroll
          for (int b = 0; b < 9; ++b){ if (kk == b) v = acc[q][b]; }
          stg[(wr+q)*9 + kk] = v;
        }
      }
      __syncthreads();

      #pragma unroll
      for (int c = 0; c < 3; ++c){
        int i = tid + c*256;
        if (i < 576){
          int b = i>>6, r = i&63, gr = rowBase + r;
          float h = 0.f;
          if (gr < NHc){
            float pre = stg[r*9 + b] + binL[r];
            #pragma unroll
            for (int cc = 0; cc < 10; ++cc) pre = fmaf(ivl[b*12 + cc], WinL[r*12 + 2 + cc], pre);
            if (s == 0) h = tanhf(pre);
            else {
              float hp = Xh[b*NHP + gr];
              float nz = (c==0)?nz0:((c==1)?nz1:nz2);
              h = 0.5f*tanhf(pre) + 0.5f*hp + nz*hp*hp;
            }
          }
          RH1[(s&7)*4608 + b*NHP + gr] = h;
        }
      }
      __syncthreads();
      if (tid == 0){
        __threadfence();                 // release
        __hip_atomic_fetch_add(myF, 1, __ATOMIC_RELEASE, __HIP_MEMORY_SCOPE_AGENT);
      }
    }
  } else if (bid < NAg + NBg) {
    // ======== stage B : h2 rows [(bid-8)*32, +32), both weights in regs ========
    float* Xh  = sm;             // [BB][NHP] (reused: h2_{s-1} then h1_s)
    float* sv  = sm + 4608;      // [288] own h2p slice
    float* stg = sm + 4896;      // [32][9]
    float* boL = sm + 5184;      // [32]
    const int rowBase = (bid - NAg) * 32;
    int* myF = &FLG[1024 + (bid - NAg)*32];
    const int wr = wave*8 + rr*2;        // 2 rows per thread
    float4 wS[2][8], wO[2][8];
    for (int q = 0; q < 2; ++q){
      int gr = rowBase + wr + q;
      for (int it = 0; it < 8; ++it){
        int jb = it*64 + kk*4;
        float4 vs = {0.f,0.f,0.f,0.f}, vo = vs;
        if (gr < NHc && jb < NHc){
          vs = *(const float4*)&Wos[gr*NHc + jb];
          vo = *(const float4*)&Wo [gr*NHc + jb];
        }
        wS[q][it] = vs; wO[q][it] = vo;
      }
    }
    if (tid < 32){ int gr = rowBase + tid; boL[tid] = (gr < NHc) ? boutp[gr] : 0.f; }
    __syncthreads();

    for (int s = 0; s < TT; ++s){
      float nz0=0.f, nz1=0.f;
      if (s > 0){
        { int i=tid, b=i>>5, r=i&31, gr=rowBase+r; if (gr<NHc) nz0=n2g[(size_t)(s-1)*4500 + b*500 + gr]; }
        if (tid < 32){ int i=tid+256, r=i&31, gr=rowBase+r; if (gr<NHc) nz1=n2g[(size_t)(s-1)*4500 + 8*500 + gr]; }
      }
      // polls (single acquire): B peers h2_{s-1}; A done step s (h1_s); C backpressure
      if (!smDead){
        bool ok = true;
        if (wave == 0){
          if (lane < NBg)        ok = waitFlag(&FLG[1024 + lane*32], s);
          else if (lane == 20){ if (s >= RGD) ok = waitFlag(&FLG[3040], s - (RGD-1)); }
        } else if (wave == 1 && lane < NAg){
          ok = waitFlag(&FLG[lane*32], s + 1);
        }
        if (!ok) smDead = 1u;
      }
      if (tid == 0) __threadfence();     // acquire (covers both ring reads)
      __syncthreads();
      if (s == 0){
        for (int i = tid; i < BB*NHP; i += 256) Xh[i] = 0.f;
      } else {
        const float4* src = (const float4*)(RH2 + ((s-1)&7)*4608);
        float4* dst = (float4*)Xh;
        for (int i = tid; i < 1152; i += 256) dst[i] = src[i];
      }
      __syncthreads();
      { int i=tid, b=i>>5, r=i&31, gr=rowBase+r; sv[i] = (gr<NHc) ? Xh[b*NHP+gr] : 0.f; }
      if (tid < 32){ int i=tid+256, r=i&31, gr=rowBase+r; sv[i] = (gr<NHc) ? Xh[8*NHP+gr] : 0.f; }

      float acc[2][9];
      for (int q = 0; q < 2; ++q)
        for (int b = 0; b < 9; ++b) acc[q][b] = 0.f;
      // self part: W_out_self @ h2_{s-1}
      #pragma unroll
      for (int it = 0; it < 8; ++it){
        int jb = it*64 + kk*4;
        #pragma unroll
        for (int b = 0; b < 9; ++b){
          float4 h = *(const float4*)&Xh[b*NHP + jb];
          #pragma unroll
          for (int q = 0; q < 2; ++q)
            acc[q][b] = fmaf(wS[q][it].x,h.x, fmaf(wS[q][it].y,h.y,
                        fmaf(wS[q][it].z,h.z, fmaf(wS[q][it].w,h.w, acc[q][b]))));
        }
      }
      __syncthreads();                   // done reading h2_{s-1}
      {
        const float4* src = (const float4*)(RH1 + (s&7)*4608);
        float4* dst = (float4*)Xh;
        for (int i = tid; i < 1152; i += 256) dst[i] = src[i];
      }
      __syncthreads();
      // out part: W_out @ h1_s (accumulates into same acc)
      #pragma unroll
      for (int it = 0; it < 8; ++it){
        int jb = it*64 + kk*4;
        #pragma unroll
        for (int b = 0; b < 9; ++b){
          float4 h = *(const float4*)&Xh[b*NHP + jb];
          #pragma unroll
          for (int q = 0; q < 2; ++q)
            acc[q][b] = fmaf(wO[q][it].x,h.x, fmaf(wO[q][it].y,h.y,
                        fmaf(wO[q][it].z,h.z, fmaf(wO[q][it].w,h.w, acc[q][b]))));
        }
      }
      #pragma unroll
      for (int mk = 1; mk < 16; mk <<= 1)
        #pragma unroll
        for (int q = 0; q < 2; ++q)
          #pragma unroll
          for (int b = 0; b < 9; ++b)
            acc[q][b] += __shfl_xor(acc[q][b], mk, 64);
      if (kk < 9){
        #pragma unroll
        for (int q = 0; q < 2; ++q){
          float v = 0.f;
          #pragma unroll
          for (int b = 0; b < 9; ++b){ if (kk == b) v = acc[q][b]; }
          stg[(wr+q)*9 + kk] = v;
        }
      }
      __syncthreads();

      #pragma unroll
      for (int c = 0; c < 2; ++c){
        int i = tid + c*256;
        if (i < 288){
          int b = i>>5, r = i&31, gr = rowBase + r;
          float h = 0.f;
          if (gr < NHc){
            float pre = stg[r*9 + b] + boL[r];
            if (s == 0) h = tanhf(pre);
            else {
              float hp = sv[i];
              float nz = (c==0)?nz0:nz1;
              h = 0.5f*tanhf(pre) + 0.5f*hp + nz*hp*hp;
            }
          }
          RH2[(s&7)*4608 + b*NHP + gr] = h;
        }
      }
      __syncthreads();
      if (tid == 0){
        __threadfence();                 // release
        __hip_atomic_fetch_add(myF, 1, __ATOMIC_RELEASE, __HIP_MEMORY_SCOPE_AGENT);
      }
    }
  } else {
    // ========== stage C : muscles + joints + output + in_vec (+6 ahead) ==========
    float* WmL  = sm;            // [6][516]
    float* Xh   = sm + 3096;     // [BB][NHP]
    float* stg  = sm + 7704;     // [4][6][9]
    float* mst  = sm + 7920;     // [BB][6]
    float* js   = sm + 7974;     // [BB][4]
    float* MaL  = sm + 8010;     // [6][2]
    float* hoL  = sm + 8022;     // [BB][2]
    int* myF = &FLG[3040];
    for (int i = tid; i < 6*512; i += 256){
      int r = i >> 9, j = i & 511;
      WmL[r*516 + j] = (j < NHc) ? Wmus[r*NHc + j] : 0.f;
    }
    if (tid < 12) MaL[tid] = Marm[tid];
    if (tid < 18) hoL[tid] = homeg[tid];
    __syncthreads();

    for (int s = 0; s < TT; ++s){
      float nz = 0.f, pv = 0.f;
      if (s > 0 && tid < 54){
        int u = tid / 9, b = tid % 9;
        nz = nmg[(size_t)(s-1)*(BB*NMc) + b*NMc + u];
      }
      if (s > 0 && tid < 18) pv = pert[(size_t)(s-1)*(BB*2) + tid];
      if (!smDead){
        bool ok = true;
        if (wave == 0 && lane < NBg) ok = waitFlag(&FLG[1024 + lane*32], s + 1);
        if (!ok) smDead = 1u;
      }
      if (tid == 0) __threadfence();     // acquire
      __syncthreads();
      {
        const float4* src = (const float4*)(RH2 + (s&7)*4608);
        float4* dst = (float4*)Xh;
        for (int i = tid; i < 1152; i += 256) dst[i] = src[i];
      }
      __syncthreads();
      {
        float a0[9], a1[9];
        for (int b = 0; b < 9; ++b){ a0[b] = 0.f; a1[b] = 0.f; }
        const int r0 = (rr < 3 ? rr : 0) * 2;
        #pragma unroll
        for (int it = 0; it < 2; ++it){
          int jb = wave*128 + it*64 + kk*4;
          float4 w0 = *(const float4*)&WmL[r0*516 + jb];
          float4 w1 = *(const float4*)&WmL[(r0+1)*516 + jb];
          #pragma unroll
          for (int b = 0; b < 9; ++b){
            float4 h = *(const float4*)&Xh[b*NHP + jb];
            a0[b] = fmaf(w0.x,h.x, fmaf(w0.y,h.y, fmaf(w0.z,h.z, fmaf(w0.w,h.w, a0[b]))));
            a1[b] = fmaf(w1.x,h.x, fmaf(w1.y,h.y, fmaf(w1.z,h.z, fmaf(w1.w,h.w, a1[b]))));
          }
        }
        #pragma unroll
        for (int mk = 1; mk < 16; mk <<= 1){
          #pragma unroll
          for (int b = 0; b < 9; ++b){
            a0[b] += __shfl_xor(a0[b], mk, 64);
            a1[b] += __shfl_xor(a1[b], mk, 64);
          }
        }
        if (kk < 9 && rr < 3){
          float v0 = 0.f, v1 = 0.f;
          #pragma unroll
          for (int b = 0; b < 9; ++b){ if (kk == b){ v0 = a0[b]; v1 = a1[b]; } }
          stg[wave*54 + (rr*2)*9   + kk] = v0;
          stg[wave*54 + (rr*2+1)*9 + kk] = v1;
        }
      }
      __syncthreads();
      if (tid < 54){
        int u = tid / 9, b = tid % 9;
        float pre = stg[u*9+b] + stg[54 + u*9+b] + stg[108 + u*9+b] + stg[162 + u*9+b];
        float rel = fmaxf(pre, 0.f);
        float mn;
        if (s == 0) mn = rel;
        else {
          float mp = mst[b*6 + u];
          mn = 0.2f*rel + 0.8f*mp + nz*mp*mp;
        }
        mst[b*6 + u] = mn;
      }
      __syncthreads();
      if (s == 0){
        if (tid < 18){
          int b = tid >> 1, c = tid & 1;
          js[b*4 + c] = hoL[b*2 + c];
          js[b*4 + 2 + c] = 0.f;
          out[b*4 + c] = hoL[b*2 + c];
          out[b*4 + 2 + c] = 0.f;
        }
      } else {
        if (tid < 18){
          int b = tid >> 1, c = tid & 1;
          float tq = 0.f;
          #pragma unroll
          for (int u = 0; u < 6; ++u) tq = fmaf(mst[b*6 + u], MaL[u*2 + c], tq);
          tq += pv;
          float v  = js[b*4 + 2 + c] + 0.01f * tq;
          float pn = js[b*4 + c] + 0.01f * v;
          js[b*4 + c] = pn;
          js[b*4 + 2 + c] = v;
          out[(size_t)s*(BB*4) + b*4 + c]     = pn;
          out[(size_t)s*(BB*4) + b*4 + 2 + c] = v;
        }
      }
      __syncthreads();
      if (tid < BB*12){
        int b = tid / 12, k = tid % 12;
        float val;
        if (k < 2)       val = 2.f * (js[b*4 + k] - hoL[b*2 + k]);
        else if (k < 4)  val = 0.5f * js[b*4 + 2 + (k - 2)];
        else if (k < 10) val = mst[b*6 + (k - 4)];
        else             val = 0.f;
        if (s == 0){
          #pragma unroll
          for (int q = 1; q <= 6; ++q) RIV[q*(BB*12) + tid] = val;
        } else {
          RIV[((s + 6) & (IVR-1))*(BB*12) + tid] = val;
        }
      }
      __syncthreads();
      if (tid == 0){
        __threadfence();                 // release
        __hip_atomic_fetch_add(myF, 1, __ATOMIC_RELEASE, __HIP_MEMORY_SCOPE_AGENT);
      }
    }
  }
}

extern "C" void kernel_launch(void* const* d_in, const int* in_sizes, int n_in,
                              void* d_out, int out_size, void* d_ws, size_t ws_size,
                              hipStream_t stream) {
  const float* pert = (const float*)d_in[1];
  const float* n1   = (const float*)d_in[2];
  const float* n2   = (const float*)d_in[3];
  const float* nm   = (const float*)d_in[4];
  const float* home = (const float*)d_in[5];
  const float* Win  = (const float*)d_in[6];
  const float* bin  = (const float*)d_in[7];
  const float* Wis  = (const float*)d_in[8];
  const float* Wo   = (const float*)d_in[9];
  const float* bout = (const float*)d_in[10];
  const float* Wos  = (const float*)d_in[11];
  const float* Wmus = (const float*)d_in[12];
  const float* Marm = (const float*)d_in[13];
  (void)in_sizes; (void)n_in; (void)out_size; (void)ws_size; // needs ~318 KB ws

  (void)hipMemsetAsync(d_ws, 0, 16384, stream);
  hipLaunchKernelGGL(fb_pipe, dim3(NAg + NBg + 1), dim3(256), 0, stream,
                     pert, n1, n2, nm, home, Win, bin, Wis, Wo, bout, Wos,
                     Wmus, Marm, (float*)d_out, (float*)d_ws);
}

// Round 9
// 25854.828 us; speedup vs baseline: 2.2527x; 1.3595x over previous
//
#include <hip/hip_runtime.h>
#include <math.h>

// ---------------- problem constants ----------------
#define TT   4096
#define BB   9
#define NHc  500
#define NHP  512
#define NMc  6
// ---------------- grid roles (workers live on ONE XCD) ----------------
#define NAg  8      // A: 64 h1 rows each, W_in_self in REGISTERS
#define NBg  16     // B: 32 h2 rows each, W_out + W_out_self in REGISTERS
#define NWRK (NAg + NBg + 1)
#define RGD  8      // h ring depth
#define IVR  16     // in_vec ring depth

// ws ints: FA[i]=32*i (i<8); FB[j]=1024+32*j (j<16); FC=3040; TICKET=3104.
#define WS_RH1 4096
#define WS_RH2 (WS_RH1 + RGD*BB*NHP)     // 40960
#define WS_RIV (WS_RH2 + RGD*BB*NHP)     // 77824 (+16*108 -> ~318KB)

// XCD-local protocol:
//  - all 25 workers on XCD0 -> ring data coherent through the SHARED per-XCD L2.
//  - publish: plain stores (write-through L1 -> L2) -> s_waitcnt vmcnt(0) ->
//    barrier -> tid0 agent-scope atomic fetch_add (executes at MALL; never
//    leaves a dirty L2 flag line, so the launch-time memset reset is safe).
//  - acquire: relaxed-agent poll (R6/R8-proven observes MALL RMWs) -> barrier ->
//    sc0 (L1-bypass) loads, served by the same L2 the producer wrote. NO fences.
__device__ __forceinline__ bool waitFlag(const int* p, int tgt){
  if (tgt <= 0) return true;
  long long n = 0;
  while (__hip_atomic_load(p, __ATOMIC_RELAXED, __HIP_MEMORY_SCOPE_AGENT) < tgt){
    __builtin_amdgcn_s_sleep(2);
    if (++n > (1LL<<20)) return false;   // safety: wrong answer instead of hang
  }
  return true;
}
// ring slice (BB*NHP floats = 2304 u64) -> LDS, sc0 = bypass L1, hit shared L2
__device__ __forceinline__ void fetchSlice(float* dstLds, const float* src, int tid){
  const unsigned long long* s64 = (const unsigned long long*)src;
  unsigned long long v0,v1,v2,v3,v4,v5,v6,v7,v8;
  asm volatile("global_load_dwordx2 %0, %1, off sc0" : "=v"(v0) : "v"(&s64[tid        ]));
  asm volatile("global_load_dwordx2 %0, %1, off sc0" : "=v"(v1) : "v"(&s64[tid +  256]));
  asm volatile("global_load_dwordx2 %0, %1, off sc0" : "=v"(v2) : "v"(&s64[tid +  512]));
  asm volatile("global_load_dwordx2 %0, %1, off sc0" : "=v"(v3) : "v"(&s64[tid +  768]));
  asm volatile("global_load_dwordx2 %0, %1, off sc0" : "=v"(v4) : "v"(&s64[tid + 1024]));
  asm volatile("global_load_dwordx2 %0, %1, off sc0" : "=v"(v5) : "v"(&s64[tid + 1280]));
  asm volatile("global_load_dwordx2 %0, %1, off sc0" : "=v"(v6) : "v"(&s64[tid + 1536]));
  asm volatile("global_load_dwordx2 %0, %1, off sc0" : "=v"(v7) : "v"(&s64[tid + 1792]));
  asm volatile("global_load_dwordx2 %0, %1, off sc0" : "=v"(v8) : "v"(&s64[tid + 2048]));
  asm volatile("s_waitcnt vmcnt(0)" ::: "memory");
  __builtin_amdgcn_sched_barrier(0);
  unsigned long long* d64 = (unsigned long long*)dstLds;
  d64[tid       ] = v0; d64[tid +  256] = v1; d64[tid +  512] = v2;
  d64[tid +  768] = v3; d64[tid + 1024] = v4; d64[tid + 1280] = v5;
  d64[tid + 1536] = v6; d64[tid + 1792] = v7; d64[tid + 2048] = v8;
}
__device__ __forceinline__ unsigned long long ld2sc0(const float* src){
  unsigned long long v;
  asm volatile("global_load_dwordx2 %0, %1, off sc0\n\ts_waitcnt vmcnt(0)"
               : "=v"(v) : "v"(src) : "memory");
  return v;
}

extern "C" __global__ void __launch_bounds__(256, 1)
fb_pipe(const float* __restrict__ pert,
        const float* __restrict__ n1g, const float* __restrict__ n2g,
        const float* __restrict__ nmg, const float* __restrict__ homeg,
        const float* __restrict__ Win,  const float* __restrict__ binp,
        const float* __restrict__ Wis,  const float* __restrict__ Wo,
        const float* __restrict__ boutp,const float* __restrict__ Wos,
        const float* __restrict__ Wmus, const float* __restrict__ Marm,
        float* __restrict__ out, float* ws)
{
  __shared__ float sm[8192];           // 32 KB, role-specific layout
  __shared__ unsigned smDead;
  __shared__ int smRank;
  int* FLG = (int*)ws;
  float* RH1 = ws + WS_RH1;
  float* RH2 = ws + WS_RH2;
  float* RIV = ws + WS_RIV;

  const int tid = threadIdx.x;
  const int wave = tid >> 6, lane = tid & 63;
  const int kk = lane & 15, rr = lane >> 4;

  // ---- claim a worker slot iff this block landed on XCD 0 ----
  if (tid == 0){
    unsigned xcc;
    asm volatile("s_getreg_b32 %0, hwreg(HW_REG_XCC_ID)" : "=s"(xcc));
    int r = -1;
    if (xcc == 0)
      r = __hip_atomic_fetch_add(&FLG[3104], 1, __ATOMIC_RELAXED, __HIP_MEMORY_SCOPE_AGENT);
    smRank = r;
    smDead = 0u;
  }
  __syncthreads();
  const int rank = smRank;
  if (rank < 0 || rank >= NWRK) return;

  if (rank < NAg) {
    // ======== stage A : h1 rows [rank*64, +64), weights in registers ========
    float* Xh   = sm;            // [BB][NHP]
    float* ivl  = sm + 4608;     // [BB][12]
    float* WinL = sm + 4716;     // [64][12]
    float* binL = sm + 5484;     // [64]
    float* stg  = sm + 5548;     // [64][9]
    const int rowBase = rank * 64;
    int* myF = &FLG[rank*32];
    const int wr = wave*16 + rr*4;       // 4 rows per thread
    float4 wreg[4][8];
    for (int q = 0; q < 4; ++q){
      int gr = rowBase + wr + q;
      for (int it = 0; it < 8; ++it){
        int jb = it*64 + kk*4;
        float4 v = {0.f,0.f,0.f,0.f};
        if (gr < NHc && jb < NHc) v = *(const float4*)&Wis[gr*NHc + jb];
        wreg[q][it] = v;
      }
    }
    for (int i = tid; i < 64*12; i += 256){
      int r = i/12, c = i%12; int gr = rowBase + r;
      WinL[i] = (gr < NHc) ? Win[gr*12 + c] : 0.f;
    }
    if (tid < 64){ int gr = rowBase + tid; binL[tid] = (gr < NHc) ? binp[gr] : 0.f; }
    __syncthreads();

    for (int s = 0; s < TT; ++s){
      float nz0=0.f, nz1=0.f, nz2=0.f;
      if (s > 0){
        { int i=tid,     b=i>>6, r=i&63, gr=rowBase+r; if (gr<NHc) nz0=n1g[(size_t)(s-1)*4500 + b*500 + gr]; }
        { int i=tid+256, b=i>>6, r=i&63, gr=rowBase+r; if (gr<NHc) nz1=n1g[(size_t)(s-1)*4500 + b*500 + gr]; }
        if (tid < 64){ int i=tid+512, b=i>>6, r=i&63, gr=rowBase+r; if (gr<NHc) nz2=n1g[(size_t)(s-1)*4500 + b*500 + gr]; }
      }
      // polls: wave0 = read gates (A peers + C in_vec); wave1 = B backpressure
      if (!smDead){
        bool ok = true;
        if (wave == 0){
          if (lane < NAg)        ok = waitFlag(&FLG[lane*32], s);
          else if (lane == 10){ int t=(s==0)?0:((s<=6)?1:(s-5)); ok = waitFlag(&FLG[3040], t); }
        } else if (wave == 1 && lane < NBg){
          if (s >= RGD) ok = waitFlag(&FLG[1024 + lane*32], s - (RGD-1));
        }
        if (!ok) smDead = 1u;
      }
      __syncthreads();
      if (s == 0){
        for (int i = tid; i < BB*NHP; i += 256) Xh[i] = 0.f;
        if (tid < 108) ivl[tid] = 0.f;
      } else {
        fetchSlice(Xh, RH1 + ((s-1)&7)*4608, tid);
        if (tid < 54){
          int b = tid/6, k0 = (tid%6)*2;
          unsigned long long v = ld2sc0(RIV + (s&15)*108 + b*12 + k0);
          *(unsigned long long*)&ivl[b*12 + k0] = v;
        }
      }
      __syncthreads();

      float acc[4][9];
      for (int q = 0; q < 4; ++q)
        for (int b = 0; b < 9; ++b) acc[q][b] = 0.f;
      #pragma unroll
      for (int it = 0; it < 8; ++it){
        int jb = it*64 + kk*4;
        #pragma unroll
        for (int b = 0; b < 9; ++b){
          float4 h = *(const float4*)&Xh[b*NHP + jb];
          #pragma unroll
          for (int q = 0; q < 4; ++q)
            acc[q][b] = fmaf(wreg[q][it].x,h.x, fmaf(wreg[q][it].y,h.y,
                        fmaf(wreg[q][it].z,h.z, fmaf(wreg[q][it].w,h.w, acc[q][b]))));
        }
      }
      #pragma unroll
      for (int mk = 1; mk < 16; mk <<= 1)
        #pragma unroll
        for (int q = 0; q < 4; ++q)
          #pragma unroll
          for (int b = 0; b < 9; ++b)
            acc[q][b] += __shfl_xor(acc[q][b], mk, 64);
      if (kk < 9){
        #pragma unroll
        for (int q = 0; q < 4; ++q){
          float v = 0.f;
          #pragma unroll
          for (int b = 0; b < 9; ++b){ if (kk == b) v = acc[q][b]; }
          stg[(wr+q)*9 + kk] = v;
        }
      }
      __syncthreads();

      const int fr = tid / 9, fb = tid % 9; (void)fr; (void)fb;
      #pragma unroll
      for (int c = 0; c < 3; ++c){
        int i = tid + c*256;
        if (i < 576){
          int b = i>>6, r = i&63, gr = rowBase + r;
          float h = 0.f;
          if (gr < NHc){
            float pre = stg[r*9 + b] + binL[r];
            #pragma unroll
            for (int cc = 0; cc < 10; ++cc) pre = fmaf(ivl[b*12 + cc], WinL[r*12 + 2 + cc], pre);
            if (s == 0) h = tanhf(pre);
            else {
              float hp = Xh[b*NHP + gr];
              float nz = (c==0)?nz0:((c==1)?nz1:nz2);
              h = 0.5f*tanhf(pre) + 0.5f*hp + nz*hp*hp;
            }
          }
          RH1[(s&7)*4608 + b*NHP + gr] = h;     // plain store -> shared L2
        }
      }
      asm volatile("s_waitcnt vmcnt(0)" ::: "memory");
      __syncthreads();
      if (tid == 0)
        __hip_atomic_fetch_add(myF, 1, __ATOMIC_RELAXED, __HIP_MEMORY_SCOPE_AGENT);
    }
  } else if (rank < NAg + NBg) {
    // ======== stage B : h2 rows [(rank-8)*32, +32), both weights in regs ========
    float* Xh  = sm;             // [BB][NHP] (reused: h2_{s-1} then h1_s)
    float* sv  = sm + 4608;      // [288]
    float* stg = sm + 4896;      // [32][9]
    float* boL = sm + 5184;      // [32]
    const int rowBase = (rank - NAg) * 32;
    int* myF = &FLG[1024 + (rank - NAg)*32];
    const int wr = wave*8 + rr*2;        // 2 rows per thread
    float4 wS[2][8], wO[2][8];
    for (int q = 0; q < 2; ++q){
      int gr = rowBase + wr + q;
      for (int it = 0; it < 8; ++it){
        int jb = it*64 + kk*4;
        float4 vs = {0.f,0.f,0.f,0.f}, vo = vs;
        if (gr < NHc && jb < NHc){
          vs = *(const float4*)&Wos[gr*NHc + jb];
          vo = *(const float4*)&Wo [gr*NHc + jb];
        }
        wS[q][it] = vs; wO[q][it] = vo;
      }
    }
    if (tid < 32){ int gr = rowBase + tid; boL[tid] = (gr < NHc) ? boutp[gr] : 0.f; }
    __syncthreads();

    for (int s = 0; s < TT; ++s){
      float nz0=0.f, nz1=0.f;
      if (s > 0){
        { int i=tid, b=i>>5, r=i&31, gr=rowBase+r; if (gr<NHc) nz0=n2g[(size_t)(s-1)*4500 + b*500 + gr]; }
        if (tid < 32){ int i=tid+256, r=i&31, gr=rowBase+r; (void)i; if (gr<NHc) nz1=n2g[(size_t)(s-1)*4500 + 8*500 + gr]; }
      }
      // polls: B peers h2_{s-1}; A done step s (h1_s); C backpressure
      if (!smDead){
        bool ok = true;
        if (wave == 0){
          if (lane < NBg)        ok = waitFlag(&FLG[1024 + lane*32], s);
          else if (lane == 20){ if (s >= RGD) ok = waitFlag(&FLG[3040], s - (RGD-1)); }
        } else if (wave == 1 && lane < NAg){
          ok = waitFlag(&FLG[lane*32], s + 1);
        }
        if (!ok) smDead = 1u;
      }
      __syncthreads();
      if (s == 0){
        for (int i = tid; i < BB*NHP; i += 256) Xh[i] = 0.f;
      } else {
        fetchSlice(Xh, RH2 + ((s-1)&7)*4608, tid);
      }
      __syncthreads();
      { int i=tid, b=i>>5, r=i&31, gr=rowBase+r; sv[i] = (gr<NHc) ? Xh[b*NHP+gr] : 0.f; }
      if (tid < 32){ int r=tid, gr=rowBase+r; sv[tid+256] = (gr<NHc) ? Xh[8*NHP+gr] : 0.f; }

      float acc[2][9];
      for (int q = 0; q < 2; ++q)
        for (int b = 0; b < 9; ++b) acc[q][b] = 0.f;
      // self part: W_out_self @ h2_{s-1}
      #pragma unroll
      for (int it = 0; it < 8; ++it){
        int jb = it*64 + kk*4;
        #pragma unroll
        for (int b = 0; b < 9; ++b){
          float4 h = *(const float4*)&Xh[b*NHP + jb];
          #pragma unroll
          for (int q = 0; q < 2; ++q)
            acc[q][b] = fmaf(wS[q][it].x,h.x, fmaf(wS[q][it].y,h.y,
                        fmaf(wS[q][it].z,h.z, fmaf(wS[q][it].w,h.w, acc[q][b]))));
        }
      }
      __syncthreads();                   // done reading h2_{s-1}
      fetchSlice(Xh, RH1 + (s&7)*4608, tid);
      __syncthreads();
      // out part: W_out @ h1_s
      #pragma unroll
      for (int it = 0; it < 8; ++it){
        int jb = it*64 + kk*4;
        #pragma unroll
        for (int b = 0; b < 9; ++b){
          float4 h = *(const float4*)&Xh[b*NHP + jb];
          #pragma unroll
          for (int q = 0; q < 2; ++q)
            acc[q][b] = fmaf(wO[q][it].x,h.x, fmaf(wO[q][it].y,h.y,
                        fmaf(wO[q][it].z,h.z, fmaf(wO[q][it].w,h.w, acc[q][b]))));
        }
      }
      #pragma unroll
      for (int mk = 1; mk < 16; mk <<= 1)
        #pragma unroll
        for (int q = 0; q < 2; ++q)
          #pragma unroll
          for (int b = 0; b < 9; ++b)
            acc[q][b] += __shfl_xor(acc[q][b], mk, 64);
      if (kk < 9){
        #pragma unroll
        for (int q = 0; q < 2; ++q){
          float v = 0.f;
          #pragma unroll
          for (int b = 0; b < 9; ++b){ if (kk == b) v = acc[q][b]; }
          stg[(wr+q)*9 + kk] = v;
        }
      }
      __syncthreads();

      #pragma unroll
      for (int c = 0; c < 2; ++c){
        int i = tid + c*256;
        if (i < 288){
          int b = i>>5, r = i&31, gr = rowBase + r;
          float h = 0.f;
          if (gr < NHc){
            float pre = stg[r*9 + b] + boL[r];
            if (s == 0) h = tanhf(pre);
            else {
              float hp = sv[i];
              float nz = (c==0)?nz0:nz1;
              h = 0.5f*tanhf(pre) + 0.5f*hp + nz*hp*hp;
            }
          }
          RH2[(s&7)*4608 + b*NHP + gr] = h;     // plain store -> shared L2
        }
      }
      asm volatile("s_waitcnt vmcnt(0)" ::: "memory");
      __syncthreads();
      if (tid == 0)
        __hip_atomic_fetch_add(myF, 1, __ATOMIC_RELAXED, __HIP_MEMORY_SCOPE_AGENT);
    }
  } else {
    // ========== stage C : muscles + joints + output + in_vec (+6 ahead) ==========
    float* WmL  = sm;            // [6][516]
    float* Xh   = sm + 3096;     // [BB][NHP]
    float* stg  = sm + 7704;     // [4][6][9]
    float* mst  = sm + 7920;     // [BB][6]
    float* js   = sm + 7974;     // [BB][4]
    float* MaL  = sm + 8010;     // [6][2]
    float* hoL  = sm + 8022;     // [BB][2]
    int* myF = &FLG[3040];
    for (int i = tid; i < 6*512; i += 256){
      int r = i >> 9, j = i & 511;
      WmL[r*516 + j] = (j < NHc) ? Wmus[r*NHc + j] : 0.f;
    }
    if (tid < 12) MaL[tid] = Marm[tid];
    if (tid < 18) hoL[tid] = homeg[tid];
    __syncthreads();

    for (int s = 0; s < TT; ++s){
      float nz = 0.f, pv = 0.f;
      if (s > 0 && tid < 54){
        int u = tid / 9, b = tid % 9;
        nz = nmg[(size_t)(s-1)*(BB*NMc) + b*NMc + u];
      }
      if (s > 0 && tid < 18) pv = pert[(size_t)(s-1)*(BB*2) + tid];
      if (!smDead){
        bool ok = true;
        if (wave == 0 && lane < NBg) ok = waitFlag(&FLG[1024 + lane*32], s + 1);
        if (!ok) smDead = 1u;
      }
      __syncthreads();
      fetchSlice(Xh, RH2 + (s&7)*4608, tid);
      __syncthreads();
      {
        float a0[9], a1[9];
        for (int b = 0; b < 9; ++b){ a0[b] = 0.f; a1[b] = 0.f; }
        const int r0 = (rr < 3 ? rr : 0) * 2;
        #pragma unroll
        for (int it = 0; it < 2; ++it){
          int jb = wave*128 + it*64 + kk*4;
          float4 w0 = *(const float4*)&WmL[r0*516 + jb];
          float4 w1 = *(const float4*)&WmL[(r0+1)*516 + jb];
          #pragma unroll
          for (int b = 0; b < 9; ++b){
            float4 h = *(const float4*)&Xh[b*NHP + jb];
            a0[b] = fmaf(w0.x,h.x, fmaf(w0.y,h.y, fmaf(w0.z,h.z, fmaf(w0.w,h.w, a0[b]))));
            a1[b] = fmaf(w1.x,h.x, fmaf(w1.y,h.y, fmaf(w1.z,h.z, fmaf(w1.w,h.w, a1[b]))));
          }
        }
        #pragma unroll
        for (int mk = 1; mk < 16; mk <<= 1){
          #pragma unroll
          for (int b = 0; b < 9; ++b){
            a0[b] += __shfl_xor(a0[b], mk, 64);
            a1[b] += __shfl_xor(a1[b], mk, 64);
          }
        }
        if (kk < 9 && rr < 3){
          float v0 = 0.f, v1 = 0.f;
          #pragma unroll
          for (int b = 0; b < 9; ++b){ if (kk == b){ v0 = a0[b]; v1 = a1[b]; } }
          stg[wave*54 + (rr*2)*9   + kk] = v0;
          stg[wave*54 + (rr*2+1)*9 + kk] = v1;
        }
      }
      __syncthreads();
      if (tid < 54){
        int u = tid / 9, b = tid % 9;
        float pre = stg[u*9+b] + stg[54 + u*9+b] + stg[108 + u*9+b] + stg[162 + u*9+b];
        float rel = fmaxf(pre, 0.f);
        float mn;
        if (s == 0) mn = rel;
        else {
          float mp = mst[b*6 + u];
          mn = 0.2f*rel + 0.8f*mp + nz*mp*mp;
        }
        mst[b*6 + u] = mn;
      }
      __syncthreads();
      if (s == 0){
        if (tid < 18){
          int b = tid >> 1, c = tid & 1;
          js[b*4 + c] = hoL[b*2 + c];
          js[b*4 + 2 + c] = 0.f;
          out[b*4 + c] = hoL[b*2 + c];
          out[b*4 + 2 + c] = 0.f;
        }
      } else {
        if (tid < 18){
          int b = tid >> 1, c = tid & 1;
          float tq = 0.f;
          #pragma unroll
          for (int u = 0; u < 6; ++u) tq = fmaf(mst[b*6 + u], MaL[u*2 + c], tq);
          tq += pv;
          float v  = js[b*4 + 2 + c] + 0.01f * tq;
          float pn = js[b*4 + c] + 0.01f * v;
          js[b*4 + c] = pn;
          js[b*4 + 2 + c] = v;
          out[(size_t)s*(BB*4) + b*4 + c]     = pn;
          out[(size_t)s*(BB*4) + b*4 + 2 + c] = v;
        }
      }
      __syncthreads();
      if (tid < BB*12){
        int b = tid / 12, k = tid % 12;
        float val;
        if (k < 2)       val = 2.f * (js[b*4 + k] - hoL[b*2 + k]);
        else if (k < 4)  val = 0.5f * js[b*4 + 2 + (k - 2)];
        else if (k < 10) val = mst[b*6 + (k - 4)];
        else             val = 0.f;
        if (s == 0){
          #pragma unroll
          for (int q = 1; q <= 6; ++q) RIV[q*(BB*12) + tid] = val;
        } else {
          RIV[((s + 6) & (IVR-1))*(BB*12) + tid] = val;
        }
      }
      asm volatile("s_waitcnt vmcnt(0)" ::: "memory");
      __syncthreads();
      if (tid == 0)
        __hip_atomic_fetch_add(myF, 1, __ATOMIC_RELAXED, __HIP_MEMORY_SCOPE_AGENT);
    }
  }
}

extern "C" void kernel_launch(void* const* d_in, const int* in_sizes, int n_in,
                              void* d_out, int out_size, void* d_ws, size_t ws_size,
                              hipStream_t stream) {
  const float* pert = (const float*)d_in[1];
  const float* n1   = (const float*)d_in[2];
  const float* n2   = (const float*)d_in[3];
  const float* nm   = (const float*)d_in[4];
  const float* home = (const float*)d_in[5];
  const float* Win  = (const float*)d_in[6];
  const float* bin  = (const float*)d_in[7];
  const float* Wis  = (const float*)d_in[8];
  const float* Wo   = (const float*)d_in[9];
  const float* bout = (const float*)d_in[10];
  const float* Wos  = (const float*)d_in[11];
  const float* Wmus = (const float*)d_in[12];
  const float* Marm = (const float*)d_in[13];
  (void)in_sizes; (void)n_in; (void)out_size; (void)ws_size; // needs ~318 KB ws

  // reset flags + ticket every launch (graph-capturable node; flags/ticket are
  // only ever written at MALL by the kernel, so this reset is never stale)
  (void)hipMemsetAsync(d_ws, 0, 16384, stream);
  // fill the whole chip so every CU gets one block; workers self-select on XCD0
  hipLaunchKernelGGL(fb_pipe, dim3(256), dim3(256), 0, stream,
                     pert, n1, n2, nm, home, Win, bin, Wis, Wo, bout, Wos,
                     Wmus, Marm, (float*)d_out, (float*)d_ws);
}